// Round 13
// baseline (30.096 us; speedup 1.0000x reference)
//
#include <hip/hip_runtime.h>
#include <math.h>
#include <stdint.h>

#define NHEAD 4
#define DD 100
#define NW 39            // word rows
#define BLOCK 256

typedef float v2f __attribute__((ext_vector_type(2)));
typedef __attribute__((address_space(3))) uint32_t lds_t;
typedef const __attribute__((address_space(1))) uint32_t glb_t;

__global__ __launch_bounds__(BLOCK, 6) void ts_enc(
    const float* __restrict__ x,       // [4800][40][100]
    const float* __restrict__ w_att,   // [4][100]
    const float* __restrict__ b_att,   // [4][100]
    float* __restrict__ out)           // [4800][400]
{
    __shared__ float tile[40 * DD];      // 16000 B: row0 = type_emb, rows 1..39 = words
    __shared__ float scp2[4][40][4];     // [wave][n][head] — b128 write, b64 read

    const int tid  = threadIdx.x;
    const int wv   = __builtin_amdgcn_readfirstlane(tid >> 6);
    const int lane = tid & 63;
    const float* xsite = x + (size_t)blockIdx.x * (40 * DD);

    // ---- stage site tile: async global->LDS, 16 B/lane, 1000 float4 chunks ----
    #pragma unroll
    for (int i = 0; i < 4; ++i) {
        const int cf = i * BLOCK + tid;
        if (cf < 1000) {
            glb_t* g = (glb_t*)(xsite + cf * 4);
            lds_t* l = (lds_t*)(tile + (i * BLOCK + wv * 64) * 4);
            __builtin_amdgcn_global_load_lds(g, l, 16, 0, 0);
        }
    }
    __syncthreads();                                   // barrier 1: tile ready

    // ---- Phase A: d-chunk split across waves, lane = n, all 4 heads, pk math ----
    // leaky(p) = max(p, 0.3p); te/w/b all wave-uniform -> scalar loads (off DS pipe)
    const bool act  = lane < NW;
    const int  nrow = act ? lane : NW - 1;             // clamp idle lanes
    const float* wrow = tile + (1 + nrow) * DD;

    v2f accA[NHEAD] = {{0,0},{0,0},{0,0},{0,0}};
    v2f accB[NHEAD] = {{0,0},{0,0},{0,0},{0,0}};

#define ABODY(cc) { \
        const int c_ = (cc); \
        const v2f x01 = *(const v2f*)(wrow + c_ * 4); \
        const v2f x23 = *(const v2f*)(wrow + c_ * 4 + 2); \
        const v2f t01 = *(const v2f*)(xsite + c_ * 4);       /* s_load (uniform) */ \
        const v2f t23 = *(const v2f*)(xsite + c_ * 4 + 2); \
        _Pragma("unroll") \
        for (int h = 0; h < NHEAD; ++h) { \
            const v2f w01 = *(const v2f*)(w_att + h * DD + c_ * 4); \
            const v2f w23 = *(const v2f*)(w_att + h * DD + c_ * 4 + 2); \
            const v2f b01 = *(const v2f*)(b_att + h * DD + c_ * 4); \
            const v2f b23 = *(const v2f*)(b_att + h * DD + c_ * 4 + 2); \
            const v2f p01 = x01 * w01 + b01; \
            const v2f p23 = x23 * w23 + b23; \
            const v2f l01 = __builtin_elementwise_max(p01, 0.3f * p01); \
            const v2f l23 = __builtin_elementwise_max(p23, 0.3f * p23); \
            accA[h] = t01 * l01 + accA[h]; \
            accB[h] = t23 * l23 + accB[h]; \
        } }

    #pragma unroll
    for (int j = 0; j < 6; ++j) ABODY(wv * 6 + j)
    if (wv == 0) ABODY(24)                             // uniform branch
#undef ABODY

    if (act) {
        float4 sc4;
        sc4.x = accA[0].x + accA[0].y + accB[0].x + accB[0].y;
        sc4.y = accA[1].x + accA[1].y + accB[1].x + accB[1].y;
        sc4.z = accA[2].x + accA[2].y + accB[2].x + accB[2].y;
        sc4.w = accA[3].x + accA[3].y + accB[3].x + accB[3].y;
        *(float4*)&scp2[wv][lane][0] = sc4;            // one b128 write
    }
    __syncthreads();                                   // barrier 2: scp2 ready

    // ---- Phases B+C: 2 role-waves (rotating with blockIdx for SIMD balance);
    //      role r handles heads {2r, 2r+1} over ALL d; other waves exit ----
    const int role = (wv + blockIdx.x) & 3;
    if (role >= 2) return;

    // Phase B: raw exp (reference math), per-head-pair score sum; NO shuffles
    v2f s01 = {0.f, 0.f};
    if (act) {
        #pragma unroll
        for (int sw = 0; sw < 4; ++sw)
            s01 += *(const v2f*)&scp2[sw][lane][2 * role];   // b64, predicated
    }
    const float e0 = act ? __expf(s01.x) : 0.f;        // lane n holds e[2r][n]
    const float e1 = act ? __expf(s01.y) : 0.f;        // lane n holds e[2r+1][n]

    // Phase C: lane = d-pair (50 active); 1 b64 words read per n serves BOTH heads;
    // denominator accumulated from the same readlane scalars
    const int l2 = lane < 50 ? lane : 49;
    const float* wb = tile + DD + l2 * 2;
    v2f o0 = {0.f, 0.f}, o1 = {0.f, 0.f};
    float s0 = 0.f, s1 = 0.f;
    #pragma unroll
    for (int n = 0; n < NW; ++n) {
        const v2f wd = *(const v2f*)(wb + n * DD);     // ds_read_b64
        const float a0 = __builtin_bit_cast(float,
            __builtin_amdgcn_readlane(__builtin_bit_cast(int, e0), n));
        const float a1 = __builtin_bit_cast(float,
            __builtin_amdgcn_readlane(__builtin_bit_cast(int, e1), n));
        o0 = a0 * wd + o0;                             // v_pk_fma, SGPR broadcast
        o1 = a1 * wd + o1;
        s0 += a0;
        s1 += a1;
    }
    const float r0 = 1.f / s0;                         // all-zero site: s=39, o=0 ✓
    const float r1 = 1.f / s1;
    if (lane < 50) {
        float* ob = out + (size_t)blockIdx.x * (NHEAD * DD) + (2 * role) * DD + lane * 2;
        const v2f q0 = o0 * r0;
        const v2f q1 = o1 * r1;
        *(v2f*)(ob)      = q0;
        *(v2f*)(ob + DD) = q1;
    }
}

extern "C" void kernel_launch(void* const* d_in, const int* in_sizes, int n_in,
                              void* d_out, int out_size, void* d_ws, size_t ws_size,
                              hipStream_t stream) {
    const float* x     = (const float*)d_in[0];
    const float* w_att = (const float*)d_in[1];
    const float* b_att = (const float*)d_in[2];
    float* out = (float*)d_out;

    const int sites = 8 * 30 * 20;   // 4800
    ts_enc<<<sites, BLOCK, 0, stream>>>(x, w_att, b_att, out);
}